// Round 15
// baseline (463.126 us; speedup 1.0000x reference)
//
#include <hip/hip_runtime.h>

// Conv2dFusion v10: v8 structure + 2-iteration barrier groups + conv2 pr-split.
// Per image: 128x128 rank-1 map
//   -> conv0(1->32) via MFMA f16 K=3 implicit GEMM (bursts of 8 pooled rows into
//      16-slot P0 ring at (i1&3)==1, i1<=25, pbase=2*i1+6)
//   -> conv1(32->64)+GELU+pool (MFMA bf16, waves 0-3, every iter) -> P1 6-row ring
//   -> conv2(64->64)+GELU+pool (MFMA bf16, waves 4-7): pr{0,1} on even i1,
//      pr{2,3}+epilogue on odd i1, acc persists (pr outermost -> FMA order identical).
// One __syncthreads per 2 iterations (ring slot disjointness re-derived for the
// no-barrier window; see notes). s_setprio(1) around MFMA clusters (T5).
// ALLOCATOR LESSON (r7/r10/r13): any config implying >=4 waves/EU (launch_bounds
// (512,4)/(1024,1) or waves_per_eu(4)) halves arch VGPR to 64 -> wf[18] spills
// ~70-350MB/dispatch. Stay at (512,2): 112-140 arch VGPR, 1 block/CU.

typedef short short8 __attribute__((ext_vector_type(8)));
typedef _Float16 half8 __attribute__((ext_vector_type(8)));
typedef float f32x4 __attribute__((ext_vector_type(4)));
typedef unsigned int uint4v __attribute__((ext_vector_type(4)));

#define OFF_TY   0                     // f32[132] = 528 B (rounded to 544)
#define OFF_H16  544                   // (126*32) * 8 B (f16 h0,h1,h2,pad) = 32256
#define OFF_P0   32800                 // 16 slots * 264 units * 16 B = 67584
#define OFF_P1   100384                // 1472 units * 16 B = 23552
#define OFF_TK   OFF_P0                // f32[128] staging, dead before first P0 write
#define LDS_TOTAL 123936

__device__ __forceinline__ unsigned short f2bf(float f) {
    unsigned int u = __float_as_uint(f);
    u += 0x7fffu + ((u >> 16) & 1u);   // RNE
    return (unsigned short)(u >> 16);
}

__device__ __forceinline__ unsigned int pack2h(float a, float b) {
    union { _Float16 h[2]; unsigned int u; } p;
    p.h[0] = (_Float16)a;
    p.h[1] = (_Float16)b;
    return p.u;
}

// erf-GELU via A&S 7.1.25 (|err| <= 2.5e-5), branch-free.
__device__ __forceinline__ float gelu_f(float x) {
    float ax = __builtin_fabsf(x);
    float E  = __builtin_amdgcn_exp2f(x * x * -0.72134752f);
    float k  = __builtin_amdgcn_rcpf(__builtin_fmaf(0.33267686f, ax, 1.0f));
    float s  = __builtin_fmaf(0.7478556f, k, -0.0958798f);
    s = __builtin_fmaf(s, k, 0.3480242f);
    s = s * k;
    float erfabs = __builtin_fmaf(-s, E, 1.0f);
    return __builtin_fmaf(0.5f * ax, erfabs, 0.5f * x);
}

// conv0 burst: pooled rows pbase..pbase+7 via MFMA f16 (A: ty window, B: H16).
// 126 units = (x-pair 0..62) x (ctile 0..1); waves 0-3 take 12, waves 4-7 take
// 20/18. Row 63 (at pbase=56) is garbage but lands in a dead ring slot.
__device__ __forceinline__ void conv0_burst(char* smem, const float* tys,
                                            int w, int l15, int lc,
                                            float b00, float b01, int pbase) {
    const int y_base = 2 * pbase;
    half8 afrag;
    {
        float a0 = tys[y_base + l15 + 0];
        float a1 = tys[y_base + l15 + 1];
        float a2 = tys[y_base + l15 + 2];
        float a3 = tys[y_base + l15 + 3];
        union { uint4v u; half8 h; } av;
        av.u = (uint4v){ pack2h(a0, a1), pack2h(a2, a3), 0u, 0u };
        afrag = av.h;   // lanes lc!=0 hold k>=8: B is zero there
    }
    const f32x4 ci0 = (f32x4){b00, b00, b00, b00};
    const f32x4 ci1 = (f32x4){b01, b01, b01, b01};
    const int base = (w < 4) ? w * 12 : 48 + (w - 4) * 20;
    const int cnt  = (w < 4) ? 12 : ((w == 7) ? 18 : 20);

    #pragma unroll
    for (int j = 0; j < 20; ++j) {
        if (j < cnt) {
            const int uid = base + j;
            const int q  = uid >> 1;
            const int ct = uid & 1;
            const char* hp = smem + OFF_H16 + ((2*q)*32 + ct*16 + l15) * 8;
            uint2 hA = *(const uint2*)(hp);
            uint2 hB = *(const uint2*)(hp + 256);   // x+1 row
            if (lc != 0) { hA.x = 0u; hA.y = 0u; hB.x = 0u; hB.y = 0u; }
            union { uint4v u; half8 h; } ba, bb;
            ba.u = (uint4v){hA.x, hA.y, 0u, 0u};
            bb.u = (uint4v){hB.x, hB.y, 0u, 0u};
            const f32x4 ci = ct ? ci1 : ci0;
            f32x4 cA = __builtin_amdgcn_mfma_f32_16x16x32_f16(afrag, ba.h, ci, 0, 0, 0);
            f32x4 cB = __builtin_amdgcn_mfma_f32_16x16x32_f16(afrag, bb.h, ci, 0, 0, 0);
            float m0 = gelu_f(fmaxf(fmaxf(cA[0], cA[1]), fmaxf(cB[0], cB[1])));
            float m1 = gelu_f(fmaxf(fmaxf(cA[2], cA[3]), fmaxf(cB[2], cB[3])));
            const int c = ct * 16 + l15;
            const int upos = (q >> 1) * 8 + ((4 * (q & 1) + (c >> 3)) ^ ((q >> 1) & 7));
            const int p0 = pbase + 2 * lc;
            const int s0 = p0 & 15, s1 = (p0 + 1) & 15;
            *(unsigned short*)(smem + OFF_P0 + (s0 * 264 + upos) * 16 + (c & 7) * 2) = f2bf(m0);
            *(unsigned short*)(smem + OFF_P0 + (s1 * 264 + upos) * 16 + (c & 7) * 2) = f2bf(m1);
        }
    }
}

__launch_bounds__(512, 2)
__global__ void conv_pipeline(const float* __restrict__ token,
                              const float* __restrict__ type_,
                              const float* __restrict__ w0, const float* __restrict__ b0,
                              const float* __restrict__ w1, const float* __restrict__ b1,
                              const float* __restrict__ w2, const float* __restrict__ b2,
                              float* __restrict__ out) {
    extern __shared__ char smem[];
    float* tys = (float*)(smem + OFF_TY);
    float* tks = (float*)(smem + OFF_TK);

    const int tid = threadIdx.x;
    const int img = blockIdx.x;
    const int w   = tid >> 6;
    const int l   = tid & 63;
    const int l15 = l & 15;
    const int lc  = l >> 4;
    const int c0w = tid & 31;

    for (int i = tid; i < 132; i += 512) {
        tys[i] = (i < 128) ? type_[img*128 + i] : 0.f;
        if (i < 128) tks[i] = token[img*128 + i];
    }

    const float b00 = b0[l15];
    const float b01 = b0[l15 + 16];

    __syncthreads();   // ty/tk visible

    // H16[x][c] = (h0,h1,h2,0) f16, h_u = sum_v w0[c,u,v]*tk[x+v]
    {
        float w0r[9];
        #pragma unroll
        for (int i = 0; i < 9; ++i) w0r[i] = w0[c0w*9 + i];
        int x = tid >> 5;
        #pragma unroll
        for (int k = 0; k < 8; ++k, x += 16) {
            if (x < 126) {
                float t0 = tks[x], t1 = tks[x+1], t2 = tks[x+2];
                float h0 = __builtin_fmaf(w0r[0],t0, __builtin_fmaf(w0r[1],t1, w0r[2]*t2));
                float h1 = __builtin_fmaf(w0r[3],t0, __builtin_fmaf(w0r[4],t1, w0r[5]*t2));
                float h2 = __builtin_fmaf(w0r[6],t0, __builtin_fmaf(w0r[7],t1, w0r[8]*t2));
                uint2 hv; hv.x = pack2h(h0, h1); hv.y = pack2h(h2, 0.f);
                *(uint2*)(smem + OFF_H16 + (x*32 + c0w)*8) = hv;
            }
        }
    }

    // Weight fragments: waves 0-3 wf[0..8] (conv1, nt=w); waves 4-7 wf[0..17].
    short8 wf[18];
    float bias;
    const int ch = ((w & 3) * 16) + l15;
    if (w < 4) {
        bias = b1[ch];
        #pragma unroll
        for (int uv = 0; uv < 9; ++uv) {
            short8 f;
            #pragma unroll
            for (int j = 0; j < 8; ++j)
                f[j] = (short)f2bf(w1[(ch*32 + 8*lc + j)*9 + uv]);
            wf[uv] = f;
        }
    } else {
        bias = b2[ch];
        #pragma unroll
        for (int kh = 0; kh < 2; ++kh)
            #pragma unroll
            for (int uv = 0; uv < 9; ++uv) {
                short8 f;
                #pragma unroll
                for (int j = 0; j < 8; ++j)
                    f[j] = (short)f2bf(w2[(ch*64 + kh*32 + 8*lc + j)*9 + uv]);
                wf[kh*9 + uv] = f;
            }
    }

    __syncthreads();   // H16 visible; tks dead (aliases P0)

    conv0_burst(smem, tys, w, l15, lc, b00, b01, 0);   // pooled rows 0..7
    __syncthreads();

    const size_t obase = (size_t)img * 12544;

    // conv2 accumulators persist across each {even,odd} iteration group.
    f32x4 c2acc[4];

    for (int i1 = 0; i1 < 30; ++i1) {
        if (w < 4) {
            // ---------- conv1 row i1: waves 0-3, nt=w, 2 passes of 2 mtiles ----------
            int rbase = (i1 % 6) * 30;
            int xr = ch >> 3;
            __builtin_amdgcn_s_setprio(1);
            #pragma unroll
            for (int half = 0; half < 2; ++half) {
                f32x4 acc[4];
                #pragma unroll
                for (int i = 0; i < 4; ++i) acc[i] = (f32x4){0.f,0.f,0.f,0.f};
                #pragma unroll
                for (int pr = 0; pr < 4; ++pr) {
                    int sbase = ((2*i1 + pr) & 15) * 264;
                    #pragma unroll
                    for (int v = 0; v < 3; ++v) {
                        #pragma unroll
                        for (int mtl = 0; mtl < 2; ++mtl) {
                            int col = (2*half + mtl)*16 + l15 + v;
                            int unit = sbase + (col>>1)*8 + ((4*(col&1) + lc) ^ ((col>>1)&7));
                            short8 a = *(const short8*)(smem + OFF_P0 + unit*16);
                            if (pr <= 2)
                                acc[mtl*2+0] = __builtin_amdgcn_mfma_f32_16x16x32_bf16(
                                    a, wf[pr*3+v], acc[mtl*2+0], 0, 0, 0);
                            if (pr >= 1)
                                acc[mtl*2+1] = __builtin_amdgcn_mfma_f32_16x16x32_bf16(
                                    a, wf[(pr-1)*3+v], acc[mtl*2+1], 0, 0, 0);
                        }
                    }
                }
                __builtin_amdgcn_s_setprio(0);
                #pragma unroll
                for (int mtl = 0; mtl < 2; ++mtl) {
                    int pcol = (2*half + mtl)*8 + lc*2;
                    if (pcol < 30) {
                        f32x4 A0 = acc[mtl*2+0], A1 = acc[mtl*2+1];
                        float p0 = fmaxf(fmaxf(A0[0], A0[1]), fmaxf(A1[0], A1[1]));
                        float p1 = fmaxf(fmaxf(A0[2], A0[3]), fmaxf(A1[2], A1[3]));
                        float m0 = gelu_f(p0 + bias);
                        float m1 = gelu_f(p1 + bias);
                        int u0 = (rbase + pcol)*8     + (xr ^ (pcol & 7));
                        int u1 = (rbase + pcol + 1)*8 + (xr ^ ((pcol+1) & 7));
                        *(unsigned short*)(smem + OFF_P1 + u0*16 + (ch&7)*2) = f2bf(m0);
                        *(unsigned short*)(smem + OFF_P1 + u1*16 + (ch&7)*2) = f2bf(m1);
                    }
                }
                if (half == 0) __builtin_amdgcn_s_setprio(1);
            }
        } else if (i1 >= 4) {
            // ---------- conv2: pr{0,1} on even i1 (init), pr{2,3}+epilogue on odd ----------
            const int i2 = (i1 - 4) >> 1;
            const int prlo = (i1 & 1) ? 2 : 0;
            if ((i1 & 1) == 0) {
                #pragma unroll
                for (int i = 0; i < 4; ++i) c2acc[i] = (f32x4){0.f,0.f,0.f,0.f};
            }
            __builtin_amdgcn_s_setprio(1);
            #pragma unroll
            for (int prr = 0; prr < 2; ++prr) {
                const int pr = prlo + prr;
                int rb = ((2*i2 + pr) % 6) * 30;
                #pragma unroll
                for (int v = 0; v < 3; ++v) {
                    #pragma unroll
                    for (int mt = 0; mt < 2; ++mt) {
                        int col = mt*16 + l15 + v;
                        #pragma unroll
                        for (int kh = 0; kh < 2; ++kh) {
                            int unit = (rb + col)*8 + ((kh*4 + lc) ^ (col & 7));
                            short8 a = *(const short8*)(smem + OFF_P1 + unit*16);
                            if (pr <= 2)
                                c2acc[mt*2+0] = __builtin_amdgcn_mfma_f32_16x16x32_bf16(
                                    a, wf[kh*9 + pr*3+v], c2acc[mt*2+0], 0, 0, 0);
                            if (pr >= 1)
                                c2acc[mt*2+1] = __builtin_amdgcn_mfma_f32_16x16x32_bf16(
                                    a, wf[kh*9 + (pr-1)*3+v], c2acc[mt*2+1], 0, 0, 0);
                        }
                    }
                }
            }
            __builtin_amdgcn_s_setprio(0);
            if (i1 & 1) {
                #pragma unroll
                for (int mt = 0; mt < 2; ++mt) {
                    int pcol = mt*8 + lc*2;
                    if (pcol < 14) {
                        f32x4 A0 = c2acc[mt*2+0], A1 = c2acc[mt*2+1];
                        float g00 = gelu_f(A0[0] + bias), g01 = gelu_f(A0[1] + bias);
                        float g02 = gelu_f(A0[2] + bias), g03 = gelu_f(A0[3] + bias);
                        float g10 = gelu_f(A1[0] + bias), g11 = gelu_f(A1[1] + bias);
                        float g12 = gelu_f(A1[2] + bias), g13 = gelu_f(A1[3] + bias);
                        float m0 = fmaxf(fmaxf(g00, g01), fmaxf(g10, g11));
                        float m1 = fmaxf(fmaxf(g02, g03), fmaxf(g12, g13));
                        float2 st; st.x = m0; st.y = m1;
                        *(float2*)(out + obase + ch*196 + i2*14 + pcol) = st;
                    }
                }
            }
        }

        // conv0 burst at (i1&3)==1, i1<=25: pooled rows 2i1+6..2i1+13.
        // Write slots (2i1+6..13)&16 are disjoint from this group's conv1 reads
        // (2i1-2..2i1+5)&16 and survive until their last reader (iter i1+5).
        if ((i1 & 3) == 1 && i1 <= 25)
            conv0_burst(smem, tys, w, l15, lc, b00, b01, 2*i1 + 6);

        if (i1 & 1) __syncthreads();   // one barrier per {even,odd} group
    }

    // tail: conv2 row 13 (P1 rows 26..29), original full-pr order
    if (w >= 4) {
        const int i2 = 13;
        f32x4 acc[4];
        #pragma unroll
        for (int i = 0; i < 4; ++i) acc[i] = (f32x4){0.f,0.f,0.f,0.f};
        #pragma unroll
        for (int pr = 0; pr < 4; ++pr) {
            int rb = ((2*i2 + pr) % 6) * 30;
            #pragma unroll
            for (int v = 0; v < 3; ++v) {
                #pragma unroll
                for (int mt = 0; mt < 2; ++mt) {
                    int col = mt*16 + l15 + v;
                    #pragma unroll
                    for (int kh = 0; kh < 2; ++kh) {
                        int unit = (rb + col)*8 + ((kh*4 + lc) ^ (col & 7));
                        short8 a = *(const short8*)(smem + OFF_P1 + unit*16);
                        if (pr <= 2)
                            acc[mt*2+0] = __builtin_amdgcn_mfma_f32_16x16x32_bf16(
                                a, wf[kh*9 + pr*3+v], acc[mt*2+0], 0, 0, 0);
                        if (pr >= 1)
                            acc[mt*2+1] = __builtin_amdgcn_mfma_f32_16x16x32_bf16(
                                a, wf[kh*9 + (pr-1)*3+v], acc[mt*2+1], 0, 0, 0);
                    }
                }
            }
        }
        #pragma unroll
        for (int mt = 0; mt < 2; ++mt) {
            int pcol = mt*8 + lc*2;
            if (pcol < 14) {
                f32x4 A0 = acc[mt*2+0], A1 = acc[mt*2+1];
                float g00 = gelu_f(A0[0] + bias), g01 = gelu_f(A0[1] + bias);
                float g02 = gelu_f(A0[2] + bias), g03 = gelu_f(A0[3] + bias);
                float g10 = gelu_f(A1[0] + bias), g11 = gelu_f(A1[1] + bias);
                float g12 = gelu_f(A1[2] + bias), g13 = gelu_f(A1[3] + bias);
                float m0 = fmaxf(fmaxf(g00, g01), fmaxf(g10, g11));
                float m1 = fmaxf(fmaxf(g02, g03), fmaxf(g12, g13));
                float2 st; st.x = m0; st.y = m1;
                *(float2*)(out + obase + ch*196 + i2*14 + pcol) = st;
            }
        }
    }
}

extern "C" void kernel_launch(void* const* d_in, const int* in_sizes, int n_in,
                              void* d_out, int out_size, void* d_ws, size_t ws_size,
                              hipStream_t stream) {
    const float* token = (const float*)d_in[0];
    const float* type_ = (const float*)d_in[1];
    const float* w0 = (const float*)d_in[2];
    const float* b0 = (const float*)d_in[3];
    const float* w1 = (const float*)d_in[4];
    const float* b1 = (const float*)d_in[5];
    const float* w2 = (const float*)d_in[6];
    const float* b2 = (const float*)d_in[7];
    float* out = (float*)d_out;

    hipLaunchKernelGGL(conv_pipeline, dim3(512), dim3(512), LDS_TOTAL, stream,
                       token, type_, w0, b0, w1, b1, w2, b2, out);
}

// Round 16
// 422.067 us; speedup vs baseline: 1.0973x; 1.0973x over previous
//
#include <hip/hip_runtime.h>

// Conv2dFusion v11: v10 schedule with the register cap LIFTED.
// ALLOCATOR RULE (r7/r10/r13/r15): __launch_bounds__ 2nd arg = min BLOCKS/CU.
// (512,2) => 4 waves/EU => 128-reg cap. LDS (124KB) caps us at 1 block/CU anyway,
// so the ",2" bought nothing and caused every spill: v8 (124 VGPR) just fit,
// v10's +16 persistent c2acc broke it (84 VGPR + 180MB scratch traffic).
// v11 = (512,1): 256-reg budget, occupancy unchanged (LDS-bound).
//   - 2-iteration barrier groups (16 barriers instead of 31), v10 ring math
//   - conv2 pr-split: pr{0,1} even i1 / pr{2,3}+epilogue odd i1, c2acc persists
//     (pr outermost -> per-output FMA order identical)
//   - conv1 single-pass acc[8] (v4 inner loop): 8 independent MFMA chains/iter
//   - s_setprio(1) around MFMA clusters
// Math per output unchanged since v8 -> absmax exactly 0.4921875.
// Spill tripwire: FETCH_SIZE >> 2 MB.

typedef short short8 __attribute__((ext_vector_type(8)));
typedef _Float16 half8 __attribute__((ext_vector_type(8)));
typedef float f32x4 __attribute__((ext_vector_type(4)));
typedef unsigned int uint4v __attribute__((ext_vector_type(4)));

#define OFF_TY   0                     // f32[132] = 528 B (rounded to 544)
#define OFF_H16  544                   // (126*32) * 8 B (f16 h0,h1,h2,pad) = 32256
#define OFF_P0   32800                 // 16 slots * 264 units * 16 B = 67584
#define OFF_P1   100384                // 1472 units * 16 B = 23552
#define OFF_TK   OFF_P0                // f32[128] staging, dead before first P0 write
#define LDS_TOTAL 123936

__device__ __forceinline__ unsigned short f2bf(float f) {
    unsigned int u = __float_as_uint(f);
    u += 0x7fffu + ((u >> 16) & 1u);   // RNE
    return (unsigned short)(u >> 16);
}

__device__ __forceinline__ unsigned int pack2h(float a, float b) {
    union { _Float16 h[2]; unsigned int u; } p;
    p.h[0] = (_Float16)a;
    p.h[1] = (_Float16)b;
    return p.u;
}

// erf-GELU via A&S 7.1.25 (|err| <= 2.5e-5), branch-free.
__device__ __forceinline__ float gelu_f(float x) {
    float ax = __builtin_fabsf(x);
    float E  = __builtin_amdgcn_exp2f(x * x * -0.72134752f);
    float k  = __builtin_amdgcn_rcpf(__builtin_fmaf(0.33267686f, ax, 1.0f));
    float s  = __builtin_fmaf(0.7478556f, k, -0.0958798f);
    s = __builtin_fmaf(s, k, 0.3480242f);
    s = s * k;
    float erfabs = __builtin_fmaf(-s, E, 1.0f);
    return __builtin_fmaf(0.5f * ax, erfabs, 0.5f * x);
}

// conv0 burst: pooled rows pbase..pbase+7 via MFMA f16 (A: ty window, B: H16).
// 126 units = (x-pair 0..62) x (ctile 0..1); waves 0-3 take 12, waves 4-7 take
// 20/18. Row 63 (at pbase=56) is garbage but lands in a dead ring slot.
__device__ __forceinline__ void conv0_burst(char* smem, const float* tys,
                                            int w, int l15, int lc,
                                            float b00, float b01, int pbase) {
    const int y_base = 2 * pbase;
    half8 afrag;
    {
        float a0 = tys[y_base + l15 + 0];
        float a1 = tys[y_base + l15 + 1];
        float a2 = tys[y_base + l15 + 2];
        float a3 = tys[y_base + l15 + 3];
        union { uint4v u; half8 h; } av;
        av.u = (uint4v){ pack2h(a0, a1), pack2h(a2, a3), 0u, 0u };
        afrag = av.h;   // lanes lc!=0 hold k>=8: B is zero there
    }
    const f32x4 ci0 = (f32x4){b00, b00, b00, b00};
    const f32x4 ci1 = (f32x4){b01, b01, b01, b01};
    const int base = (w < 4) ? w * 12 : 48 + (w - 4) * 20;
    const int cnt  = (w < 4) ? 12 : ((w == 7) ? 18 : 20);

    #pragma unroll
    for (int j = 0; j < 20; ++j) {
        if (j < cnt) {
            const int uid = base + j;
            const int q  = uid >> 1;
            const int ct = uid & 1;
            const char* hp = smem + OFF_H16 + ((2*q)*32 + ct*16 + l15) * 8;
            uint2 hA = *(const uint2*)(hp);
            uint2 hB = *(const uint2*)(hp + 256);   // x+1 row
            if (lc != 0) { hA.x = 0u; hA.y = 0u; hB.x = 0u; hB.y = 0u; }
            union { uint4v u; half8 h; } ba, bb;
            ba.u = (uint4v){hA.x, hA.y, 0u, 0u};
            bb.u = (uint4v){hB.x, hB.y, 0u, 0u};
            const f32x4 ci = ct ? ci1 : ci0;
            f32x4 cA = __builtin_amdgcn_mfma_f32_16x16x32_f16(afrag, ba.h, ci, 0, 0, 0);
            f32x4 cB = __builtin_amdgcn_mfma_f32_16x16x32_f16(afrag, bb.h, ci, 0, 0, 0);
            float m0 = gelu_f(fmaxf(fmaxf(cA[0], cA[1]), fmaxf(cB[0], cB[1])));
            float m1 = gelu_f(fmaxf(fmaxf(cA[2], cA[3]), fmaxf(cB[2], cB[3])));
            const int c = ct * 16 + l15;
            const int upos = (q >> 1) * 8 + ((4 * (q & 1) + (c >> 3)) ^ ((q >> 1) & 7));
            const int p0 = pbase + 2 * lc;
            const int s0 = p0 & 15, s1 = (p0 + 1) & 15;
            *(unsigned short*)(smem + OFF_P0 + (s0 * 264 + upos) * 16 + (c & 7) * 2) = f2bf(m0);
            *(unsigned short*)(smem + OFF_P0 + (s1 * 264 + upos) * 16 + (c & 7) * 2) = f2bf(m1);
        }
    }
}

__launch_bounds__(512, 1)
__global__ void conv_pipeline(const float* __restrict__ token,
                              const float* __restrict__ type_,
                              const float* __restrict__ w0, const float* __restrict__ b0,
                              const float* __restrict__ w1, const float* __restrict__ b1,
                              const float* __restrict__ w2, const float* __restrict__ b2,
                              float* __restrict__ out) {
    extern __shared__ char smem[];
    float* tys = (float*)(smem + OFF_TY);
    float* tks = (float*)(smem + OFF_TK);

    const int tid = threadIdx.x;
    const int img = blockIdx.x;
    const int w   = tid >> 6;
    const int l   = tid & 63;
    const int l15 = l & 15;
    const int lc  = l >> 4;
    const int c0w = tid & 31;

    for (int i = tid; i < 132; i += 512) {
        tys[i] = (i < 128) ? type_[img*128 + i] : 0.f;
        if (i < 128) tks[i] = token[img*128 + i];
    }

    const float b00 = b0[l15];
    const float b01 = b0[l15 + 16];

    __syncthreads();   // ty/tk visible

    // H16[x][c] = (h0,h1,h2,0) f16, h_u = sum_v w0[c,u,v]*tk[x+v]
    {
        float w0r[9];
        #pragma unroll
        for (int i = 0; i < 9; ++i) w0r[i] = w0[c0w*9 + i];
        int x = tid >> 5;
        #pragma unroll
        for (int k = 0; k < 8; ++k, x += 16) {
            if (x < 126) {
                float t0 = tks[x], t1 = tks[x+1], t2 = tks[x+2];
                float h0 = __builtin_fmaf(w0r[0],t0, __builtin_fmaf(w0r[1],t1, w0r[2]*t2));
                float h1 = __builtin_fmaf(w0r[3],t0, __builtin_fmaf(w0r[4],t1, w0r[5]*t2));
                float h2 = __builtin_fmaf(w0r[6],t0, __builtin_fmaf(w0r[7],t1, w0r[8]*t2));
                uint2 hv; hv.x = pack2h(h0, h1); hv.y = pack2h(h2, 0.f);
                *(uint2*)(smem + OFF_H16 + (x*32 + c0w)*8) = hv;
            }
        }
    }

    // Weight fragments: waves 0-3 wf[0..8] (conv1, nt=w); waves 4-7 wf[0..17].
    short8 wf[18];
    float bias;
    const int ch = ((w & 3) * 16) + l15;
    if (w < 4) {
        bias = b1[ch];
        #pragma unroll
        for (int uv = 0; uv < 9; ++uv) {
            short8 f;
            #pragma unroll
            for (int j = 0; j < 8; ++j)
                f[j] = (short)f2bf(w1[(ch*32 + 8*lc + j)*9 + uv]);
            wf[uv] = f;
        }
    } else {
        bias = b2[ch];
        #pragma unroll
        for (int kh = 0; kh < 2; ++kh)
            #pragma unroll
            for (int uv = 0; uv < 9; ++uv) {
                short8 f;
                #pragma unroll
                for (int j = 0; j < 8; ++j)
                    f[j] = (short)f2bf(w2[(ch*64 + kh*32 + 8*lc + j)*9 + uv]);
                wf[kh*9 + uv] = f;
            }
    }

    __syncthreads();   // H16 visible; tks dead (aliases P0)

    conv0_burst(smem, tys, w, l15, lc, b00, b01, 0);   // pooled rows 0..7
    __syncthreads();

    const size_t obase = (size_t)img * 12544;

    // conv2 accumulators persist across each {even,odd} iteration group.
    f32x4 c2acc[4];

    for (int i1 = 0; i1 < 30; ++i1) {
        if (w < 4) {
            // ---------- conv1 row i1: waves 0-3, nt=w, single pass acc[8] ----------
            int rbase = (i1 % 6) * 30;
            int xr = ch >> 3;
            f32x4 acc[8];   // [mt][row]
            #pragma unroll
            for (int i = 0; i < 8; ++i) acc[i] = (f32x4){0.f,0.f,0.f,0.f};
            __builtin_amdgcn_s_setprio(1);
            #pragma unroll
            for (int pr = 0; pr < 4; ++pr) {
                int sbase = ((2*i1 + pr) & 15) * 264;
                #pragma unroll
                for (int v = 0; v < 3; ++v) {
                    #pragma unroll
                    for (int mt = 0; mt < 4; ++mt) {
                        int col = mt*16 + l15 + v;
                        int unit = sbase + (col>>1)*8 + ((4*(col&1) + lc) ^ ((col>>1)&7));
                        short8 a = *(const short8*)(smem + OFF_P0 + unit*16);
                        if (pr <= 2)
                            acc[mt*2+0] = __builtin_amdgcn_mfma_f32_16x16x32_bf16(
                                a, wf[pr*3+v], acc[mt*2+0], 0, 0, 0);
                        if (pr >= 1)
                            acc[mt*2+1] = __builtin_amdgcn_mfma_f32_16x16x32_bf16(
                                a, wf[(pr-1)*3+v], acc[mt*2+1], 0, 0, 0);
                    }
                }
            }
            __builtin_amdgcn_s_setprio(0);
            // epilogue: premax -> +bias -> GELU -> P1 ring row i1%6
            #pragma unroll
            for (int mt = 0; mt < 4; ++mt) {
                int pcol = mt*8 + lc*2;
                if (pcol < 30) {
                    f32x4 A0 = acc[mt*2+0], A1 = acc[mt*2+1];
                    float p0 = fmaxf(fmaxf(A0[0], A0[1]), fmaxf(A1[0], A1[1]));
                    float p1 = fmaxf(fmaxf(A0[2], A0[3]), fmaxf(A1[2], A1[3]));
                    float m0 = gelu_f(p0 + bias);
                    float m1 = gelu_f(p1 + bias);
                    int u0 = (rbase + pcol)*8     + (xr ^ (pcol & 7));
                    int u1 = (rbase + pcol + 1)*8 + (xr ^ ((pcol+1) & 7));
                    *(unsigned short*)(smem + OFF_P1 + u0*16 + (ch&7)*2) = f2bf(m0);
                    *(unsigned short*)(smem + OFF_P1 + u1*16 + (ch&7)*2) = f2bf(m1);
                }
            }
        } else if (i1 >= 4) {
            // ---------- conv2: pr{0,1} on even i1 (init), pr{2,3}+epilogue on odd ----------
            const int i2 = (i1 - 4) >> 1;
            const int prlo = (i1 & 1) ? 2 : 0;
            if ((i1 & 1) == 0) {
                #pragma unroll
                for (int i = 0; i < 4; ++i) c2acc[i] = (f32x4){0.f,0.f,0.f,0.f};
            }
            __builtin_amdgcn_s_setprio(1);
            #pragma unroll
            for (int prr = 0; prr < 2; ++prr) {
                const int pr = prlo + prr;
                int rb = ((2*i2 + pr) % 6) * 30;
                #pragma unroll
                for (int v = 0; v < 3; ++v) {
                    #pragma unroll
                    for (int mt = 0; mt < 2; ++mt) {
                        int col = mt*16 + l15 + v;
                        #pragma unroll
                        for (int kh = 0; kh < 2; ++kh) {
                            int unit = (rb + col)*8 + ((kh*4 + lc) ^ (col & 7));
                            short8 a = *(const short8*)(smem + OFF_P1 + unit*16);
                            if (pr <= 2)
                                c2acc[mt*2+0] = __builtin_amdgcn_mfma_f32_16x16x32_bf16(
                                    a, wf[kh*9 + pr*3+v], c2acc[mt*2+0], 0, 0, 0);
                            if (pr >= 1)
                                c2acc[mt*2+1] = __builtin_amdgcn_mfma_f32_16x16x32_bf16(
                                    a, wf[kh*9 + (pr-1)*3+v], c2acc[mt*2+1], 0, 0, 0);
                        }
                    }
                }
            }
            __builtin_amdgcn_s_setprio(0);
            if (i1 & 1) {
                #pragma unroll
                for (int mt = 0; mt < 2; ++mt) {
                    int pcol = mt*8 + lc*2;
                    if (pcol < 14) {
                        f32x4 A0 = c2acc[mt*2+0], A1 = c2acc[mt*2+1];
                        float g00 = gelu_f(A0[0] + bias), g01 = gelu_f(A0[1] + bias);
                        float g02 = gelu_f(A0[2] + bias), g03 = gelu_f(A0[3] + bias);
                        float g10 = gelu_f(A1[0] + bias), g11 = gelu_f(A1[1] + bias);
                        float g12 = gelu_f(A1[2] + bias), g13 = gelu_f(A1[3] + bias);
                        float m0 = fmaxf(fmaxf(g00, g01), fmaxf(g10, g11));
                        float m1 = fmaxf(fmaxf(g02, g03), fmaxf(g12, g13));
                        float2 st; st.x = m0; st.y = m1;
                        *(float2*)(out + obase + ch*196 + i2*14 + pcol) = st;
                    }
                }
            }
        }

        // conv0 burst at (i1&3)==1, i1<=25: pooled rows 2i1+6..2i1+13.
        // Write slots disjoint from the group's conv1 read slots (2i1-2..2i1+5)&15.
        if ((i1 & 3) == 1 && i1 <= 25)
            conv0_burst(smem, tys, w, l15, lc, b00, b01, 2*i1 + 6);

        if (i1 & 1) __syncthreads();   // one barrier per {even,odd} group
    }

    // tail: conv2 row 13 (P1 rows 26..29), original full-pr order
    if (w >= 4) {
        const int i2 = 13;
        f32x4 acc[4];
        #pragma unroll
        for (int i = 0; i < 4; ++i) acc[i] = (f32x4){0.f,0.f,0.f,0.f};
        #pragma unroll
        for (int pr = 0; pr < 4; ++pr) {
            int rb = ((2*i2 + pr) % 6) * 30;
            #pragma unroll
            for (int v = 0; v < 3; ++v) {
                #pragma unroll
                for (int mt = 0; mt < 2; ++mt) {
                    int col = mt*16 + l15 + v;
                    #pragma unroll
                    for (int kh = 0; kh < 2; ++kh) {
                        int unit = (rb + col)*8 + ((kh*4 + lc) ^ (col & 7));
                        short8 a = *(const short8*)(smem + OFF_P1 + unit*16);
                        if (pr <= 2)
                            acc[mt*2+0] = __builtin_amdgcn_mfma_f32_16x16x32_bf16(
                                a, wf[kh*9 + pr*3+v], acc[mt*2+0], 0, 0, 0);
                        if (pr >= 1)
                            acc[mt*2+1] = __builtin_amdgcn_mfma_f32_16x16x32_bf16(
                                a, wf[kh*9 + (pr-1)*3+v], acc[mt*2+1], 0, 0, 0);
                    }
                }
            }
        }
        #pragma unroll
        for (int mt = 0; mt < 2; ++mt) {
            int pcol = mt*8 + lc*2;
            if (pcol < 14) {
                f32x4 A0 = acc[mt*2+0], A1 = acc[mt*2+1];
                float g00 = gelu_f(A0[0] + bias), g01 = gelu_f(A0[1] + bias);
                float g02 = gelu_f(A0[2] + bias), g03 = gelu_f(A0[3] + bias);
                float g10 = gelu_f(A1[0] + bias), g11 = gelu_f(A1[1] + bias);
                float g12 = gelu_f(A1[2] + bias), g13 = gelu_f(A1[3] + bias);
                float m0 = fmaxf(fmaxf(g00, g01), fmaxf(g10, g11));
                float m1 = fmaxf(fmaxf(g02, g03), fmaxf(g12, g13));
                float2 st; st.x = m0; st.y = m1;
                *(float2*)(out + obase + ch*196 + i2*14 + pcol) = st;
            }
        }
    }
}

extern "C" void kernel_launch(void* const* d_in, const int* in_sizes, int n_in,
                              void* d_out, int out_size, void* d_ws, size_t ws_size,
                              hipStream_t stream) {
    const float* token = (const float*)d_in[0];
    const float* type_ = (const float*)d_in[1];
    const float* w0 = (const float*)d_in[2];
    const float* b0 = (const float*)d_in[3];
    const float* w1 = (const float*)d_in[4];
    const float* b1 = (const float*)d_in[5];
    const float* w2 = (const float*)d_in[6];
    const float* b2 = (const float*)d_in[7];
    float* out = (float*)d_out;

    hipLaunchKernelGGL(conv_pipeline, dim3(512), dim3(512), LDS_TOTAL, stream,
                       token, type_, w0, b0, w1, b1, w2, b2, out);
}

// Round 17
// 182.091 us; speedup vs baseline: 2.5434x; 2.3179x over previous
//
#include <hip/hip_runtime.h>

// Conv2dFusion v12: v8 schedule + 2-row barrier groups, ALL wf indices static.
// ALLOCATOR TRAPS (mapped r7/r10/r13/r15/r16):
//   (1) __launch_bounds__ 2nd arg = min BLOCKS/CU; >=4 waves/EU => <=128 unified
//       regs => wf[18] (72 regs) spills (~150-350MB scratch traffic).
//   (2) amdgpu_waves_per_eu(4): same cap, same spill.
//   (3) RUNTIME index into wf (v10/v11 conv2 pr-split: pr = (i1&1?2:0)+prr) =>
//       whole array demoted to scratch (rule #20): VGPR 124->88, ~100MB FETCH
//       and WRITE. ALL wf[] indices must be compile-time literals.
// v12: (512,1) (LDS 124KB caps at 1 block/CU anyway; 256-reg budget);
//   group ig = rows {2ig, 2ig+1}, ONE barrier per group (16 total):
//   - conv1 waves (0-3): rows 2ig and 2ig+1, single-pass acc[8] (8 MFMA chains)
//   - conv2 waves (4-7): full row i2=ig-2 (static pr 0..3), local acc[4]
//   - conv0 burst at even ig<=12, pbase=4ig+8 (P0 slots +8..+15 vs reads +0..+5
//     mod 16 disjoint; P1 writes {2ig,2ig+1}%6 vs conv2 reads {2ig-4..2ig-1}%6)
// Math per output unchanged since v8 -> absmax exactly 0.4921875.
// Spill tripwire: FETCH_SIZE >> 2 MB.

typedef short short8 __attribute__((ext_vector_type(8)));
typedef _Float16 half8 __attribute__((ext_vector_type(8)));
typedef float f32x4 __attribute__((ext_vector_type(4)));
typedef unsigned int uint4v __attribute__((ext_vector_type(4)));

#define OFF_TY   0                     // f32[132] = 528 B (rounded to 544)
#define OFF_H16  544                   // (126*32) * 8 B (f16 h0,h1,h2,pad) = 32256
#define OFF_P0   32800                 // 16 slots * 264 units * 16 B = 67584
#define OFF_P1   100384                // 1472 units * 16 B = 23552
#define OFF_TK   OFF_P0                // f32[128] staging, dead before first P0 write
#define LDS_TOTAL 123936

__device__ __forceinline__ unsigned short f2bf(float f) {
    unsigned int u = __float_as_uint(f);
    u += 0x7fffu + ((u >> 16) & 1u);   // RNE
    return (unsigned short)(u >> 16);
}

__device__ __forceinline__ unsigned int pack2h(float a, float b) {
    union { _Float16 h[2]; unsigned int u; } p;
    p.h[0] = (_Float16)a;
    p.h[1] = (_Float16)b;
    return p.u;
}

// erf-GELU via A&S 7.1.25 (|err| <= 2.5e-5), branch-free.
__device__ __forceinline__ float gelu_f(float x) {
    float ax = __builtin_fabsf(x);
    float E  = __builtin_amdgcn_exp2f(x * x * -0.72134752f);
    float k  = __builtin_amdgcn_rcpf(__builtin_fmaf(0.33267686f, ax, 1.0f));
    float s  = __builtin_fmaf(0.7478556f, k, -0.0958798f);
    s = __builtin_fmaf(s, k, 0.3480242f);
    s = s * k;
    float erfabs = __builtin_fmaf(-s, E, 1.0f);
    return __builtin_fmaf(0.5f * ax, erfabs, 0.5f * x);
}

// conv0 burst: pooled rows pbase..pbase+7 via MFMA f16 (A: ty window, B: H16).
// 126 units = (x-pair 0..62) x (ctile 0..1); waves 0-3 take 12, waves 4-7 take
// 20/18. Row 63 (at pbase=56) is garbage but lands in a dead ring slot.
__device__ __forceinline__ void conv0_burst(char* smem, const float* tys,
                                            int w, int l15, int lc,
                                            float b00, float b01, int pbase) {
    const int y_base = 2 * pbase;
    half8 afrag;
    {
        float a0 = tys[y_base + l15 + 0];
        float a1 = tys[y_base + l15 + 1];
        float a2 = tys[y_base + l15 + 2];
        float a3 = tys[y_base + l15 + 3];
        union { uint4v u; half8 h; } av;
        av.u = (uint4v){ pack2h(a0, a1), pack2h(a2, a3), 0u, 0u };
        afrag = av.h;   // lanes lc!=0 hold k>=8: B is zero there
    }
    const f32x4 ci0 = (f32x4){b00, b00, b00, b00};
    const f32x4 ci1 = (f32x4){b01, b01, b01, b01};
    const int base = (w < 4) ? w * 12 : 48 + (w - 4) * 20;
    const int cnt  = (w < 4) ? 12 : ((w == 7) ? 18 : 20);

    #pragma unroll
    for (int j = 0; j < 20; ++j) {
        if (j < cnt) {
            const int uid = base + j;
            const int q  = uid >> 1;
            const int ct = uid & 1;
            const char* hp = smem + OFF_H16 + ((2*q)*32 + ct*16 + l15) * 8;
            uint2 hA = *(const uint2*)(hp);
            uint2 hB = *(const uint2*)(hp + 256);   // x+1 row
            if (lc != 0) { hA.x = 0u; hA.y = 0u; hB.x = 0u; hB.y = 0u; }
            union { uint4v u; half8 h; } ba, bb;
            ba.u = (uint4v){hA.x, hA.y, 0u, 0u};
            bb.u = (uint4v){hB.x, hB.y, 0u, 0u};
            const f32x4 ci = ct ? ci1 : ci0;
            f32x4 cA = __builtin_amdgcn_mfma_f32_16x16x32_f16(afrag, ba.h, ci, 0, 0, 0);
            f32x4 cB = __builtin_amdgcn_mfma_f32_16x16x32_f16(afrag, bb.h, ci, 0, 0, 0);
            float m0 = gelu_f(fmaxf(fmaxf(cA[0], cA[1]), fmaxf(cB[0], cB[1])));
            float m1 = gelu_f(fmaxf(fmaxf(cA[2], cA[3]), fmaxf(cB[2], cB[3])));
            const int c = ct * 16 + l15;
            const int upos = (q >> 1) * 8 + ((4 * (q & 1) + (c >> 3)) ^ ((q >> 1) & 7));
            const int p0 = pbase + 2 * lc;
            const int s0 = p0 & 15, s1 = (p0 + 1) & 15;
            *(unsigned short*)(smem + OFF_P0 + (s0 * 264 + upos) * 16 + (c & 7) * 2) = f2bf(m0);
            *(unsigned short*)(smem + OFF_P0 + (s1 * 264 + upos) * 16 + (c & 7) * 2) = f2bf(m1);
        }
    }
}

__launch_bounds__(512, 1)
__global__ void conv_pipeline(const float* __restrict__ token,
                              const float* __restrict__ type_,
                              const float* __restrict__ w0, const float* __restrict__ b0,
                              const float* __restrict__ w1, const float* __restrict__ b1,
                              const float* __restrict__ w2, const float* __restrict__ b2,
                              float* __restrict__ out) {
    extern __shared__ char smem[];
    float* tys = (float*)(smem + OFF_TY);
    float* tks = (float*)(smem + OFF_TK);

    const int tid = threadIdx.x;
    const int img = blockIdx.x;
    const int w   = tid >> 6;
    const int l   = tid & 63;
    const int l15 = l & 15;
    const int lc  = l >> 4;
    const int c0w = tid & 31;

    for (int i = tid; i < 132; i += 512) {
        tys[i] = (i < 128) ? type_[img*128 + i] : 0.f;
        if (i < 128) tks[i] = token[img*128 + i];
    }

    const float b00 = b0[l15];
    const float b01 = b0[l15 + 16];

    __syncthreads();   // ty/tk visible

    // H16[x][c] = (h0,h1,h2,0) f16, h_u = sum_v w0[c,u,v]*tk[x+v]
    {
        float w0r[9];
        #pragma unroll
        for (int i = 0; i < 9; ++i) w0r[i] = w0[c0w*9 + i];
        int x = tid >> 5;
        #pragma unroll
        for (int k = 0; k < 8; ++k, x += 16) {
            if (x < 126) {
                float t0 = tks[x], t1 = tks[x+1], t2 = tks[x+2];
                float h0 = __builtin_fmaf(w0r[0],t0, __builtin_fmaf(w0r[1],t1, w0r[2]*t2));
                float h1 = __builtin_fmaf(w0r[3],t0, __builtin_fmaf(w0r[4],t1, w0r[5]*t2));
                float h2 = __builtin_fmaf(w0r[6],t0, __builtin_fmaf(w0r[7],t1, w0r[8]*t2));
                uint2 hv; hv.x = pack2h(h0, h1); hv.y = pack2h(h2, 0.f);
                *(uint2*)(smem + OFF_H16 + (x*32 + c0w)*8) = hv;
            }
        }
    }

    // Weight fragments: waves 0-3 wf[0..8] (conv1, nt=w); waves 4-7 wf[0..17].
    short8 wf[18];
    float bias;
    const int ch = ((w & 3) * 16) + l15;
    if (w < 4) {
        bias = b1[ch];
        #pragma unroll
        for (int uv = 0; uv < 9; ++uv) {
            short8 f;
            #pragma unroll
            for (int j = 0; j < 8; ++j)
                f[j] = (short)f2bf(w1[(ch*32 + 8*lc + j)*9 + uv]);
            wf[uv] = f;
        }
    } else {
        bias = b2[ch];
        #pragma unroll
        for (int kh = 0; kh < 2; ++kh)
            #pragma unroll
            for (int uv = 0; uv < 9; ++uv) {
                short8 f;
                #pragma unroll
                for (int j = 0; j < 8; ++j)
                    f[j] = (short)f2bf(w2[(ch*64 + kh*32 + 8*lc + j)*9 + uv]);
                wf[kh*9 + uv] = f;
            }
    }

    __syncthreads();   // H16 visible; tks dead (aliases P0)

    conv0_burst(smem, tys, w, l15, lc, b00, b01, 0);   // pooled rows 0..7 (slots 0..7)
    __syncthreads();

    const size_t obase = (size_t)img * 12544;

    for (int ig = 0; ig < 15; ++ig) {
        if (w < 4) {
            // ---------- conv1 rows 2ig, 2ig+1: waves 0-3, nt=w, acc[8] ----------
            #pragma unroll
            for (int ph = 0; ph < 2; ++ph) {
                const int i1 = 2*ig + ph;
                int rbase = (i1 % 6) * 30;
                int xr = ch >> 3;
                f32x4 acc[8];   // [mt][row]
                #pragma unroll
                for (int i = 0; i < 8; ++i) acc[i] = (f32x4){0.f,0.f,0.f,0.f};
                __builtin_amdgcn_s_setprio(1);
                #pragma unroll
                for (int pr = 0; pr < 4; ++pr) {
                    int sbase = ((2*i1 + pr) & 15) * 264;
                    #pragma unroll
                    for (int v = 0; v < 3; ++v) {
                        #pragma unroll
                        for (int mt = 0; mt < 4; ++mt) {
                            int col = mt*16 + l15 + v;
                            int unit = sbase + (col>>1)*8 + ((4*(col&1) + lc) ^ ((col>>1)&7));
                            short8 a = *(const short8*)(smem + OFF_P0 + unit*16);
                            if (pr <= 2)
                                acc[mt*2+0] = __builtin_amdgcn_mfma_f32_16x16x32_bf16(
                                    a, wf[pr*3+v], acc[mt*2+0], 0, 0, 0);
                            if (pr >= 1)
                                acc[mt*2+1] = __builtin_amdgcn_mfma_f32_16x16x32_bf16(
                                    a, wf[(pr-1)*3+v], acc[mt*2+1], 0, 0, 0);
                        }
                    }
                }
                __builtin_amdgcn_s_setprio(0);
                // epilogue: premax -> +bias -> GELU -> P1 ring row i1%6
                #pragma unroll
                for (int mt = 0; mt < 4; ++mt) {
                    int pcol = mt*8 + lc*2;
                    if (pcol < 30) {
                        f32x4 A0 = acc[mt*2+0], A1 = acc[mt*2+1];
                        float p0 = fmaxf(fmaxf(A0[0], A0[1]), fmaxf(A1[0], A1[1]));
                        float p1 = fmaxf(fmaxf(A0[2], A0[3]), fmaxf(A1[2], A1[3]));
                        float m0 = gelu_f(p0 + bias);
                        float m1 = gelu_f(p1 + bias);
                        int u0 = (rbase + pcol)*8     + (xr ^ (pcol & 7));
                        int u1 = (rbase + pcol + 1)*8 + (xr ^ ((pcol+1) & 7));
                        *(unsigned short*)(smem + OFF_P1 + u0*16 + (ch&7)*2) = f2bf(m0);
                        *(unsigned short*)(smem + OFF_P1 + u1*16 + (ch&7)*2) = f2bf(m1);
                    }
                }
            }
        } else if (ig >= 2) {
            // ---------- conv2 row i2 = ig-2: waves 4-7, nt=w-4, static pr ----------
            const int i2 = ig - 2;
            f32x4 acc[4];
            #pragma unroll
            for (int i = 0; i < 4; ++i) acc[i] = (f32x4){0.f,0.f,0.f,0.f};
            __builtin_amdgcn_s_setprio(1);
            #pragma unroll
            for (int pr = 0; pr < 4; ++pr) {
                int rb = ((2*i2 + pr) % 6) * 30;
                #pragma unroll
                for (int v = 0; v < 3; ++v) {
                    #pragma unroll
                    for (int mt = 0; mt < 2; ++mt) {
                        int col = mt*16 + l15 + v;
                        #pragma unroll
                        for (int kh = 0; kh < 2; ++kh) {
                            int unit = (rb + col)*8 + ((kh*4 + lc) ^ (col & 7));
                            short8 a = *(const short8*)(smem + OFF_P1 + unit*16);
                            if (pr <= 2)
                                acc[mt*2+0] = __builtin_amdgcn_mfma_f32_16x16x32_bf16(
                                    a, wf[kh*9 + pr*3+v], acc[mt*2+0], 0, 0, 0);
                            if (pr >= 1)
                                acc[mt*2+1] = __builtin_amdgcn_mfma_f32_16x16x32_bf16(
                                    a, wf[kh*9 + (pr-1)*3+v], acc[mt*2+1], 0, 0, 0);
                        }
                    }
                }
            }
            __builtin_amdgcn_s_setprio(0);
            // epilogue: exact GELU x8 then max -> out
            #pragma unroll
            for (int mt = 0; mt < 2; ++mt) {
                int pcol = mt*8 + lc*2;
                if (pcol < 14) {
                    f32x4 A0 = acc[mt*2+0], A1 = acc[mt*2+1];
                    float g00 = gelu_f(A0[0] + bias), g01 = gelu_f(A0[1] + bias);
                    float g02 = gelu_f(A0[2] + bias), g03 = gelu_f(A0[3] + bias);
                    float g10 = gelu_f(A1[0] + bias), g11 = gelu_f(A1[1] + bias);
                    float g12 = gelu_f(A1[2] + bias), g13 = gelu_f(A1[3] + bias);
                    float m0 = fmaxf(fmaxf(g00, g01), fmaxf(g10, g11));
                    float m1 = fmaxf(fmaxf(g02, g03), fmaxf(g12, g13));
                    float2 st; st.x = m0; st.y = m1;
                    *(float2*)(out + obase + ch*196 + i2*14 + pcol) = st;
                }
            }
        }

        // conv0 burst at even ig<=12: pooled rows 4ig+8..4ig+15.
        // P0 write slots (4ig+8..15)&15 vs group read slots (4ig..4ig+5)&15: disjoint.
        // Overwritten rows 4ig-8..4ig-1 were last read in group ig-1 (barrier'd).
        if (((ig & 1) == 0) && ig <= 12)
            conv0_burst(smem, tys, w, l15, lc, b00, b01, 4*ig + 8);

        __syncthreads();   // one barrier per 2-row group
    }

    // tail: conv2 row 13 (P1 rows 26..29, written in groups 13/14, barrier'd)
    if (w >= 4) {
        const int i2 = 13;
        f32x4 acc[4];
        #pragma unroll
        for (int i = 0; i < 4; ++i) acc[i] = (f32x4){0.f,0.f,0.f,0.f};
        #pragma unroll
        for (int pr = 0; pr < 4; ++pr) {
            int rb = ((2*i2 + pr) % 6) * 30;
            #pragma unroll
            for (int v = 0; v < 3; ++v) {
                #pragma unroll
                for (int mt = 0; mt < 2; ++mt) {
                    int col = mt*16 + l15 + v;
                    #pragma unroll
                    for (int kh = 0; kh < 2; ++kh) {
                        int unit = (rb + col)*8 + ((kh*4 + lc) ^ (col & 7));
                        short8 a = *(const short8*)(smem + OFF_P1 + unit*16);
                        if (pr <= 2)
                            acc[mt*2+0] = __builtin_amdgcn_mfma_f32_16x16x32_bf16(
                                a, wf[kh*9 + pr*3+v], acc[mt*2+0], 0, 0, 0);
                        if (pr >= 1)
                            acc[mt*2+1] = __builtin_amdgcn_mfma_f32_16x16x32_bf16(
                                a, wf[kh*9 + (pr-1)*3+v], acc[mt*2+1], 0, 0, 0);
                    }
                }
            }
        }
        #pragma unroll
        for (int mt = 0; mt < 2; ++mt) {
            int pcol = mt*8 + lc*2;
            if (pcol < 14) {
                f32x4 A0 = acc[mt*2+0], A1 = acc[mt*2+1];
                float g00 = gelu_f(A0[0] + bias), g01 = gelu_f(A0[1] + bias);
                float g02 = gelu_f(A0[2] + bias), g03 = gelu_f(A0[3] + bias);
                float g10 = gelu_f(A1[0] + bias), g11 = gelu_f(A1[1] + bias);
                float g12 = gelu_f(A1[2] + bias), g13 = gelu_f(A1[3] + bias);
                float m0 = fmaxf(fmaxf(g00, g01), fmaxf(g10, g11));
                float m1 = fmaxf(fmaxf(g02, g03), fmaxf(g12, g13));
                float2 st; st.x = m0; st.y = m1;
                *(float2*)(out + obase + ch*196 + i2*14 + pcol) = st;
            }
        }
    }
}

extern "C" void kernel_launch(void* const* d_in, const int* in_sizes, int n_in,
                              void* d_out, int out_size, void* d_ws, size_t ws_size,
                              hipStream_t stream) {
    const float* token = (const float*)d_in[0];
    const float* type_ = (const float*)d_in[1];
    const float* w0 = (const float*)d_in[2];
    const float* b0 = (const float*)d_in[3];
    const float* w1 = (const float*)d_in[4];
    const float* b1 = (const float*)d_in[5];
    const float* w2 = (const float*)d_in[6];
    const float* b2 = (const float*)d_in[7];
    float* out = (float*)d_out;

    hipLaunchKernelGGL(conv_pipeline, dim3(512), dim3(512), LDS_TOTAL, stream,
                       token, type_, w0, b0, w1, b1, w2, b2, out);
}